// Round 5
// baseline (246.397 us; speedup 1.0000x reference)
//
#include <hip/hip_runtime.h>
#include <hip/hip_bf16.h>

#define T_ 4096
#define C_ 1024
#define H_ 64
#define LSTR 72  // P-buffer LDS row stride: mult-of-8 keeps 16B alignment, breaks pow2 banks

typedef short bf16x8 __attribute__((ext_vector_type(8)));
typedef float f32x4 __attribute__((ext_vector_type(4)));

__device__ __forceinline__ short f2bf(float f) {
  union { __hip_bfloat16 h; short s; } u;
  u.h = __float2bfloat16(f);
  return u.s;
}
__device__ __forceinline__ unsigned pack2(float a, float b) {
  return ((unsigned)(unsigned short)f2bf(b) << 16) | (unsigned short)f2bf(a);
}

// ---- kernel 0: W[c][h] fp32 -> Wt[n][c] bf16, n in [0,192): 0-63=K, 64-127=Q, 128-191=V
__global__ void wtrans_kernel(const float* __restrict__ Wk,
                              const float* __restrict__ Wq,
                              const float* __restrict__ Wv,
                              __hip_bfloat16* __restrict__ Wt) {
  int tid = blockIdx.x * 256 + threadIdx.x;
  if (tid >= 192 * 1024) return;
  int n = tid >> 10;
  int c = tid & 1023;
  const float* W = (n < 64) ? Wk : ((n < 128) ? Wq : Wv);
  Wt[tid] = __float2bfloat16(W[c * 64 + (n & 63)]);
}

// ---- kernel 1: qkv projection, in-block split-K.
// 1024 blocks = one 16-row tile each; 4 waves split C=1024 into 256 each (8 chunks),
// fp32 partials reduced via LDS atomicAdd into tile[16][192], then coalesced
// store phase emits q row-major + Kf/Vf in MFMA-frag order (R3-verified swizzle).
// 4 blocks/CU -> 16 waves/CU; x read ONCE.
__global__ __launch_bounds__(256, 4) void proj_kernel(
    const float* __restrict__ x, const __hip_bfloat16* __restrict__ Wt,
    __hip_bfloat16* __restrict__ qb, __hip_bfloat16* __restrict__ Kf,
    __hip_bfloat16* __restrict__ Vf) {
  __shared__ float tile[16 * 192];
  const int tid = threadIdx.x;
  const int lane = tid & 63;
  const int wave = tid >> 6;
  const int m = lane & 15;
  const int quad = lane >> 4;
  const int rt = blockIdx.x;      // row tile 0..1023
  const int t0 = rt * 16;

  // zero the reduction tile
#pragma unroll
  for (int i = 0; i < 12; ++i) tile[tid + i * 256] = 0.f;
  __syncthreads();

  f32x4 acc[12];  // 0-3: K cols, 4-7: Q cols, 8-11: V cols
#pragma unroll
  for (int i = 0; i < 12; ++i) acc[i] = (f32x4){0.f, 0.f, 0.f, 0.f};

  const float* xrow = x + (size_t)(t0 + m) * C_ + wave * 256 + quad * 8;
  const __hip_bfloat16* wrow = Wt + (size_t)m * C_ + wave * 256 + quad * 8;

  // depth-4 software pipeline on the x stream (8 outstanding float4/lane)
  float4 pa[4], pb[4];
#pragma unroll
  for (int i = 0; i < 4; ++i) {
    pa[i] = *(const float4*)(xrow + i * 32);
    pb[i] = *(const float4*)(xrow + i * 32 + 4);
  }

#pragma unroll
  for (int c = 0; c < 8; ++c) {
    const int slot = c & 3;
    const int kc = c * 32;
    bf16x8 a;
    a[0] = f2bf(pa[slot].x); a[1] = f2bf(pa[slot].y);
    a[2] = f2bf(pa[slot].z); a[3] = f2bf(pa[slot].w);
    a[4] = f2bf(pb[slot].x); a[5] = f2bf(pb[slot].y);
    a[6] = f2bf(pb[slot].z); a[7] = f2bf(pb[slot].w);
    if (c < 4) {  // refill 4 chunks ahead
      pa[slot] = *(const float4*)(xrow + kc + 128);
      pb[slot] = *(const float4*)(xrow + kc + 132);
    }
#pragma unroll
    for (int nt = 0; nt < 12; ++nt) {
      bf16x8 bfrag = *(const bf16x8*)(wrow + (size_t)nt * 16 * C_ + kc);
      acc[nt] = __builtin_amdgcn_mfma_f32_16x16x32_bf16(a, bfrag, acc[nt], 0, 0, 0);
    }
  }

  // reduce the 4 wave-partials: C-layout (row=quad*4+r, col=nt*16+m)
#pragma unroll
  for (int nt = 0; nt < 12; ++nt)
#pragma unroll
    for (int r = 0; r < 4; ++r)
      atomicAdd(&tile[(quad * 4 + r) * 192 + nt * 16 + m], acc[nt][r]);
  __syncthreads();

  // ---- store phase (256 threads, 12 elems each), dst-contiguous ----
  const int bb = t0 >> 12;
  const int tloc = t0 & (T_ - 1);
  const int ktile = tloc >> 6;

  // Q: cols 64..127 of tile -> qb[t][h] row-major
  {
    const int row = tid >> 4;
    const int h0 = (tid & 15) * 4;
    const float* src = &tile[row * 192 + 64 + h0];
    unsigned lo = pack2(src[0], src[1]);
    unsigned hi = pack2(src[2], src[3]);
    uint2 u = {lo, hi};
    *(uint2*)(qb + (size_t)(t0 + row) * H_ + h0) = u;
  }
  // K: cols 0..63 -> frag order; this tile covers 2 contiguous 512-elem segments
  {
    __hip_bfloat16* dst = Kf + ((size_t)bb * 64 + ktile) * 4096;
    const int ntK = (tloc >> 4) & 3;
    const int idx = tid * 4;
    const int wh = idx >> 9;
    const int o = idx & 511;
    const int quadK = o >> 7;
    const int rK = (o >> 3) & 15;
    const int j0 = o & 7;
    const int h = wh * 32 + quadK * 8 + j0;
    const float* src = &tile[rK * 192 + h];
    unsigned lo = pack2(src[0], src[1]);
    unsigned hi = pack2(src[2], src[3]);
    uint2 u = {lo, hi};
    *(uint2*)(dst + (ntK * 2 + wh) * 512 + o) = u;
  }
  // V: cols 128..191 -> frag order; 8 contiguous 128-elem segments
  {
    __hip_bfloat16* dst = Vf + ((size_t)bb * 64 + ktile) * 4096;
    const int o0 = tloc & 63;
    const int half = (o0 >> 5) & 1;
    const int qv0 = (o0 >> 3) & 3;
    const int idx = tid * 4;
    const int nt = idx >> 8;
    const int o = idx & 255;
    const int dq = o >> 7;
    const int u8 = o & 127;
    const int mV = u8 >> 3;
    const int j0 = u8 & 7;
    float v0 = tile[(dq * 8 + j0 + 0) * 192 + 128 + nt * 16 + mV];
    float v1 = tile[(dq * 8 + j0 + 1) * 192 + 128 + nt * 16 + mV];
    float v2 = tile[(dq * 8 + j0 + 2) * 192 + 128 + nt * 16 + mV];
    float v3 = tile[(dq * 8 + j0 + 3) * 192 + 128 + nt * 16 + mV];
    unsigned lo = pack2(v0, v1);
    unsigned hi = pack2(v2, v3);
    uint2 u = {lo, hi};
    *(uint2*)(dst + (nt * 2 + half) * 512 + (qv0 + dq) * 128 + u8) = u;
  }
}

// ---- kernel 2: flash pass1, split-KV. 4608 wave-jobs = (b, qtile16, chunk512).
// All K/V frag loads are lane*16B coalesced bursts from the pre-swizzled Kf/Vf.
__global__ __launch_bounds__(256, 4) void fa_pass1(
    const __hip_bfloat16* __restrict__ qb, const __hip_bfloat16* __restrict__ Kf,
    const __hip_bfloat16* __restrict__ Vf, float* __restrict__ Opart,
    float* __restrict__ Ml) {
  __shared__ __hip_bfloat16 Pl[4][16 * LSTR];
  const int lane = threadIdx.x & 63;
  const int wave = threadIdx.x >> 6;
  const int m = lane & 15;
  const int quad = lane >> 4;

  const int jid = blockIdx.x * 4 + wave;  // 0..4607
  const int b = jid / 1152;
  const int j2 = jid - b * 1152;
  int g = 7;
  while (16 * g * (g + 1) > j2) --g;      // qtile group: nc = g+1 chunks
  const int r2 = j2 - 16 * g * (g + 1);
  const int qt = 32 * g + r2 / (g + 1);
  const int c = r2 - (r2 / (g + 1)) * (g + 1);
  const int q0 = qt * 16;
  const int k0s = c * 512;
  const int kend0 = k0s + 512;
  const int kend = (kend0 < q0 + 16) ? kend0 : (q0 + 16);
  const int ntile = (kend - k0s + 63) >> 6;

  const __hip_bfloat16* qbase = qb + ((size_t)b * T_ + q0 + m) * H_;
  bf16x8 qf0 = *(const bf16x8*)(qbase + quad * 8);
  bf16x8 qf1 = *(const bf16x8*)(qbase + 32 + quad * 8);

  f32x4 Oacc[4];
#pragma unroll
  for (int i = 0; i < 4; ++i) Oacc[i] = (f32x4){0.f, 0.f, 0.f, 0.f};
  float mrow[4], lrow[4];
#pragma unroll
  for (int r = 0; r < 4; ++r) { mrow[r] = -__builtin_inff(); lrow[r] = 0.f; }

  const __hip_bfloat16* kgf = Kf + (size_t)b * 262144 + lane * 8;
  const __hip_bfloat16* vgf = Vf + (size_t)b * 262144 + lane * 8;
  const float cscale = 0.18033688011112042f;  // log2(e)/sqrt(64)
  __hip_bfloat16* Plw = &Pl[wave][0];

  for (int it = 0; it < ntile; ++it) {
    const int ktile = (k0s >> 6) + it;
    const int k0 = ktile * 64;
    const __hip_bfloat16* kp = kgf + (size_t)ktile * 4096;
    const __hip_bfloat16* vp = vgf + (size_t)ktile * 4096;

    // S = Q K^T — coalesced frag loads
    f32x4 s[4];
#pragma unroll
    for (int nt = 0; nt < 4; ++nt) {
      bf16x8 kf0 = *(const bf16x8*)(kp + nt * 1024);
      bf16x8 kf1 = *(const bf16x8*)(kp + nt * 1024 + 512);
      f32x4 t = (f32x4){0.f, 0.f, 0.f, 0.f};
      t = __builtin_amdgcn_mfma_f32_16x16x32_bf16(qf0, kf0, t, 0, 0, 0);
      t = __builtin_amdgcn_mfma_f32_16x16x32_bf16(qf1, kf1, t, 0, 0, 0);
      s[nt] = t;
    }

    // V frags issued NOW (no data dependency): latency hides under softmax
    bf16x8 vf[8];
#pragma unroll
    for (int nt = 0; nt < 4; ++nt) {
      vf[2 * nt] = *(const bf16x8*)(vp + nt * 1024);
      vf[2 * nt + 1] = *(const bf16x8*)(vp + nt * 1024 + 512);
    }

    // scale to exp2 domain + causal mask (only diagonal-crossing tile)
    float xs[4][4];
    const bool needmask = (k0 + 63 > q0);
#pragma unroll
    for (int nt = 0; nt < 4; ++nt)
#pragma unroll
      for (int r = 0; r < 4; ++r) {
        float xv = s[nt][r] * cscale;
        if (needmask && (k0 + nt * 16 + m) > (q0 + quad * 4 + r))
          xv = -__builtin_inff();
        xs[nt][r] = xv;
      }

    float mnew[4], alpha[4];
#pragma unroll
    for (int r = 0; r < 4; ++r) {
      float v = fmaxf(fmaxf(xs[0][r], xs[1][r]), fmaxf(xs[2][r], xs[3][r]));
      v = fmaxf(v, __shfl_xor(v, 1));
      v = fmaxf(v, __shfl_xor(v, 2));
      v = fmaxf(v, __shfl_xor(v, 4));
      v = fmaxf(v, __shfl_xor(v, 8));
      mnew[r] = fmaxf(mrow[r], v);
      alpha[r] = exp2f(mrow[r] - mnew[r]);
      mrow[r] = mnew[r];
    }

    float psum[4] = {0.f, 0.f, 0.f, 0.f};
#pragma unroll
    for (int nt = 0; nt < 4; ++nt)
#pragma unroll
      for (int r = 0; r < 4; ++r) {
        float p = exp2f(xs[nt][r] - mnew[r]);
        psum[r] += p;
        Plw[(quad * 4 + r) * LSTR + nt * 16 + m] = __float2bfloat16(p);
      }
#pragma unroll
    for (int r = 0; r < 4; ++r) {
      float v = psum[r];
      v += __shfl_xor(v, 1);
      v += __shfl_xor(v, 2);
      v += __shfl_xor(v, 4);
      v += __shfl_xor(v, 8);
      lrow[r] = lrow[r] * alpha[r] + v;
    }
#pragma unroll
    for (int nt = 0; nt < 4; ++nt)
#pragma unroll
      for (int r = 0; r < 4; ++r) Oacc[nt][r] *= alpha[r];

    // O += P V
    bf16x8 pf0 = *(const bf16x8*)(&Plw[m * LSTR + quad * 8]);
    bf16x8 pf1 = *(const bf16x8*)(&Plw[m * LSTR + 32 + quad * 8]);
#pragma unroll
    for (int nt = 0; nt < 4; ++nt) {
      Oacc[nt] = __builtin_amdgcn_mfma_f32_16x16x32_bf16(pf0, vf[2 * nt], Oacc[nt], 0, 0, 0);
      Oacc[nt] = __builtin_amdgcn_mfma_f32_16x16x32_bf16(pf1, vf[2 * nt + 1], Oacc[nt], 0, 0, 0);
    }
  }

  float* Op = Opart + (size_t)jid * 1024;
#pragma unroll
  for (int nt = 0; nt < 4; ++nt)
#pragma unroll
    for (int r = 0; r < 4; ++r)
      Op[(quad * 4 + r) * 64 + nt * 16 + m] = Oacc[nt][r];
  if (m == 0) {
#pragma unroll
    for (int r = 0; r < 4; ++r) {
      Ml[(size_t)jid * 32 + quad * 4 + r] = mrow[r];
      Ml[(size_t)jid * 32 + 16 + quad * 4 + r] = lrow[r];
    }
  }
}

// ---- kernel 3: combine partials. 1024 WGs = (b, qtile16); thread = (row, 4 h's).
__global__ __launch_bounds__(256) void fa_combine(
    const float* __restrict__ Opart, const float* __restrict__ Ml,
    float* __restrict__ out) {
  const int bq = blockIdx.x;
  const int b = bq >> 8;
  const int qt = bq & 255;
  const int g = qt >> 5;
  const int nc = g + 1;
  const int jbase = b * 1152 + 16 * g * (g + 1) + (qt & 31) * nc;
  const int r = threadIdx.x >> 4;
  const int h0 = (threadIdx.x & 15) * 4;

  float M = -__builtin_inff();
  for (int c = 0; c < nc; ++c) {
    float mv = Ml[(size_t)(jbase + c) * 32 + r];
    M = fmaxf(M, mv);
  }
  float4 O = {0.f, 0.f, 0.f, 0.f};
  float L = 0.f;
  for (int c = 0; c < nc; ++c) {
    float mv = Ml[(size_t)(jbase + c) * 32 + r];
    float lv = Ml[(size_t)(jbase + c) * 32 + 16 + r];
    float w = exp2f(mv - M);
    float4 o = *(const float4*)(Opart + (size_t)(jbase + c) * 1024 + r * 64 + h0);
    O.x += w * o.x; O.y += w * o.y; O.z += w * o.z; O.w += w * o.w;
    L += w * lv;
  }
  float inv = 1.f / L;
  float4 res = {O.x * inv, O.y * inv, O.z * inv, O.w * inv};
  *(float4*)(out + ((size_t)b * T_ + qt * 16 + r) * H_ + h0) = res;
}

extern "C" void kernel_launch(void* const* d_in, const int* in_sizes, int n_in,
                              void* d_out, int out_size, void* d_ws, size_t ws_size,
                              hipStream_t stream) {
  const float* x = (const float*)d_in[0];
  const float* Wk = (const float*)d_in[1];
  const float* Wq = (const float*)d_in[2];
  const float* Wv = (const float*)d_in[3];
  float* out = (float*)d_out;
  char* ws = (char*)d_ws;
  // ws: Wt[192][1024]bf16 | qb[4][4096][64]bf16 | Kf[4][64][4096]bf16(frag order)
  //     | Vf same | Opart[4608][16][64]f32 | Ml[4608][2][16]f32   (~26.1 MB)
  __hip_bfloat16* Wt = (__hip_bfloat16*)ws;
  __hip_bfloat16* qb = (__hip_bfloat16*)(ws + 393216);
  __hip_bfloat16* Kf = (__hip_bfloat16*)(ws + 2490368);
  __hip_bfloat16* Vf = (__hip_bfloat16*)(ws + 4587520);
  float* Opart = (float*)(ws + 6684672);
  float* Ml = (float*)(ws + 25559040);

  hipLaunchKernelGGL(wtrans_kernel, dim3(768), dim3(256), 0, stream, Wk, Wq, Wv, Wt);
  hipLaunchKernelGGL(proj_kernel, dim3(1024), dim3(256), 0, stream, x, Wt, qb, Kf, Vf);
  hipLaunchKernelGGL(fa_pass1, dim3(1152), dim3(256), 0, stream, qb, Kf, Vf, Opart, Ml);
  hipLaunchKernelGGL(fa_combine, dim3(1024), dim3(256), 0, stream, Opart, Ml, out);
}

// Round 6
// 186.958 us; speedup vs baseline: 1.3179x; 1.3179x over previous
//
#include <hip/hip_runtime.h>
#include <hip/hip_bf16.h>

#define T_ 4096
#define C_ 1024
#define H_ 64
#define LSTR 72   // P-buffer LDS row stride (bf16 elems)
#define XSTR 132  // x-tile LDS row stride (fp32 elems): m*132%32 = m*4 -> 2-way, free

typedef short bf16x8 __attribute__((ext_vector_type(8)));
typedef float f32x4 __attribute__((ext_vector_type(4)));

__device__ __forceinline__ short f2bf(float f) {
  union { __hip_bfloat16 h; short s; } u;
  u.h = __float2bfloat16(f);
  return u.s;
}

// ---- kernel 0: W[c][h] fp32 -> Wt[n][c] bf16, n in [0,192): 0-63=K, 64-127=Q, 128-191=V
__global__ void wtrans_kernel(const float* __restrict__ Wk,
                              const float* __restrict__ Wq,
                              const float* __restrict__ Wv,
                              __hip_bfloat16* __restrict__ Wt) {
  int tid = blockIdx.x * 256 + threadIdx.x;
  if (tid >= 192 * 1024) return;
  int n = tid >> 10;
  int c = tid & 1023;
  const float* W = (n < 64) ? Wk : ((n < 128) ? Wq : Wv);
  Wt[tid] = __float2bfloat16(W[c * 64 + (n & 63)]);
}

// ---- kernel 1: qkv projection, producer-consumer.
// 1024 blocks = one 16-row tile each. Wave 3 stages x (fp32) into double-buffered
// LDS with fully coalesced loads; waves 0/1/2 compute K/Q/V (R3-proven structure:
// 4 accs, 4 B-frag L2 streams each) reading A-frags from LDS. x read ONCE.
__global__ __launch_bounds__(256) void proj_kernel(
    const float* __restrict__ x, const __hip_bfloat16* __restrict__ Wt,
    __hip_bfloat16* __restrict__ qb, __hip_bfloat16* __restrict__ Kf,
    __hip_bfloat16* __restrict__ Vf) {
  __shared__ float Xl[2][16 * XSTR];  // 16 rows x 128 cols fp32 per buffer
  const int tid = threadIdx.x;
  const int lane = tid & 63;
  const int wave = tid >> 6;
  const int m = lane & 15;
  const int quad = lane >> 4;
  const int rt = blockIdx.x;  // row tile 0..1023
  const int t0 = rt * 16;

  const float* xbase = x + (size_t)t0 * C_;

  // prologue: stage chunk 0
  if (wave == 3) {
#pragma unroll
    for (int i = 0; i < 8; ++i) {
      const int linear = i * 64 + lane;       // 512 float4 per chunk
      const int row = linear >> 5;            // 32 float4 per row
      const int c4 = linear & 31;
      float4 v = *(const float4*)(xbase + (size_t)row * C_ + c4 * 4);
      *(float4*)&Xl[0][row * XSTR + c4 * 4] = v;
    }
  }
  __syncthreads();

  f32x4 acc[4];
#pragma unroll
  for (int i = 0; i < 4; ++i) acc[i] = (f32x4){0.f, 0.f, 0.f, 0.f};

  const int which = wave;  // 0=K 1=Q 2=V (wave 3 = stager)
  const __hip_bfloat16* wrow = Wt + ((size_t)which * 64 + m) * C_ + quad * 8;

  for (int c = 0; c < 8; ++c) {
    if (wave == 3) {
      if (c + 1 < 8) {
        const float* src = xbase + (c + 1) * 128;
        float* dst = &Xl[(c + 1) & 1][0];
#pragma unroll
        for (int i = 0; i < 8; ++i) {
          const int linear = i * 64 + lane;
          const int row = linear >> 5;
          const int c4 = linear & 31;
          float4 v = *(const float4*)(src + (size_t)row * C_ + c4 * 4);
          *(float4*)&dst[row * XSTR + c4 * 4] = v;
        }
      }
    } else {
      const float* xl = &Xl[c & 1][m * XSTR + quad * 8];
#pragma unroll
      for (int ks = 0; ks < 4; ++ks) {
        float4 xa = *(const float4*)(xl + ks * 32);
        float4 xb = *(const float4*)(xl + ks * 32 + 4);
        bf16x8 a;
        a[0] = f2bf(xa.x); a[1] = f2bf(xa.y); a[2] = f2bf(xa.z); a[3] = f2bf(xa.w);
        a[4] = f2bf(xb.x); a[5] = f2bf(xb.y); a[6] = f2bf(xb.z); a[7] = f2bf(xb.w);
        const int kc = c * 128 + ks * 32;
#pragma unroll
        for (int nt = 0; nt < 4; ++nt) {
          bf16x8 bfrag = *(const bf16x8*)(wrow + (size_t)nt * 16 * C_ + kc);
          acc[nt] = __builtin_amdgcn_mfma_f32_16x16x32_bf16(a, bfrag, acc[nt], 0, 0, 0);
        }
      }
    }
    __syncthreads();
  }

  const int bb = t0 >> 12;
  const int tloc = t0 & (T_ - 1);
  const int ktile = tloc >> 6;

  if (which == 1) {  // Q: row-major [t][h]
#pragma unroll
    for (int nt = 0; nt < 4; ++nt)
#pragma unroll
      for (int r = 0; r < 4; ++r)
        qb[(size_t)(t0 + quad * 4 + r) * H_ + nt * 16 + m] = __float2bfloat16(acc[nt][r]);
  } else if (which == 0) {  // K -> frag order (R3-verified swizzle)
    __hip_bfloat16* dst = Kf + ((size_t)bb * 64 + ktile) * 4096;
    const int ntK = (tloc >> 4) & 3;
#pragma unroll
    for (int nt = 0; nt < 4; ++nt) {
      const int wh = nt >> 1;                     // h>>5
      const int quadK = (nt * 2 + (m >> 3)) & 3;  // (h>>3)&3
      const int j = m & 7;
#pragma unroll
      for (int r = 0; r < 4; ++r) {
        const int mK = quad * 4 + r;              // kvo&15
        dst[(ntK * 2 + wh) * 512 + (quadK * 16 + mK) * 8 + j] = __float2bfloat16(acc[nt][r]);
      }
    }
  } else if (which == 2) {  // V -> frag order (R3-verified swizzle)
    __hip_bfloat16* dst = Vf + ((size_t)bb * 64 + ktile) * 4096;
#pragma unroll
    for (int nt = 0; nt < 4; ++nt) {
#pragma unroll
      for (int r = 0; r < 4; ++r) {
        const int kvo = (tloc & 63) + quad * 4 + r;
        const int half = (kvo >> 5) & 1;
        const int quadV = (kvo >> 3) & 3;
        const int j = kvo & 7;
        dst[(nt * 2 + half) * 512 + (quadV * 16 + m) * 8 + j] = __float2bfloat16(acc[nt][r]);
      }
    }
  }
}

// ---- kernel 2: flash pass1, split-KV. 4608 wave-jobs = (b, qtile16, chunk512).
// All K/V frag loads are lane*16B coalesced bursts from the pre-swizzled Kf/Vf.
__global__ __launch_bounds__(256, 4) void fa_pass1(
    const __hip_bfloat16* __restrict__ qb, const __hip_bfloat16* __restrict__ Kf,
    const __hip_bfloat16* __restrict__ Vf, float* __restrict__ Opart,
    float* __restrict__ Ml) {
  __shared__ __hip_bfloat16 Pl[4][16 * LSTR];
  const int lane = threadIdx.x & 63;
  const int wave = threadIdx.x >> 6;
  const int m = lane & 15;
  const int quad = lane >> 4;

  const int jid = blockIdx.x * 4 + wave;  // 0..4607
  const int b = jid / 1152;
  const int j2 = jid - b * 1152;
  int g = 7;
  while (16 * g * (g + 1) > j2) --g;      // qtile group: nc = g+1 chunks
  const int r2 = j2 - 16 * g * (g + 1);
  const int qt = 32 * g + r2 / (g + 1);
  const int c = r2 - (r2 / (g + 1)) * (g + 1);
  const int q0 = qt * 16;
  const int k0s = c * 512;
  const int kend0 = k0s + 512;
  const int kend = (kend0 < q0 + 16) ? kend0 : (q0 + 16);
  const int ntile = (kend - k0s + 63) >> 6;

  const __hip_bfloat16* qbase = qb + ((size_t)b * T_ + q0 + m) * H_;
  bf16x8 qf0 = *(const bf16x8*)(qbase + quad * 8);
  bf16x8 qf1 = *(const bf16x8*)(qbase + 32 + quad * 8);

  f32x4 Oacc[4];
#pragma unroll
  for (int i = 0; i < 4; ++i) Oacc[i] = (f32x4){0.f, 0.f, 0.f, 0.f};
  float mrow[4], lrow[4];
#pragma unroll
  for (int r = 0; r < 4; ++r) { mrow[r] = -__builtin_inff(); lrow[r] = 0.f; }

  const __hip_bfloat16* kgf = Kf + (size_t)b * 262144 + lane * 8;
  const __hip_bfloat16* vgf = Vf + (size_t)b * 262144 + lane * 8;
  const float cscale = 0.18033688011112042f;  // log2(e)/sqrt(64)
  __hip_bfloat16* Plw = &Pl[wave][0];

  for (int it = 0; it < ntile; ++it) {
    const int ktile = (k0s >> 6) + it;
    const int k0 = ktile * 64;
    const __hip_bfloat16* kp = kgf + (size_t)ktile * 4096;
    const __hip_bfloat16* vp = vgf + (size_t)ktile * 4096;

    // S = Q K^T — coalesced frag loads
    f32x4 s[4];
#pragma unroll
    for (int nt = 0; nt < 4; ++nt) {
      bf16x8 kf0 = *(const bf16x8*)(kp + nt * 1024);
      bf16x8 kf1 = *(const bf16x8*)(kp + nt * 1024 + 512);
      f32x4 t = (f32x4){0.f, 0.f, 0.f, 0.f};
      t = __builtin_amdgcn_mfma_f32_16x16x32_bf16(qf0, kf0, t, 0, 0, 0);
      t = __builtin_amdgcn_mfma_f32_16x16x32_bf16(qf1, kf1, t, 0, 0, 0);
      s[nt] = t;
    }

    // V frags issued NOW (no data dependency): latency hides under softmax
    bf16x8 vf[8];
#pragma unroll
    for (int nt = 0; nt < 4; ++nt) {
      vf[2 * nt] = *(const bf16x8*)(vp + nt * 1024);
      vf[2 * nt + 1] = *(const bf16x8*)(vp + nt * 1024 + 512);
    }

    // scale to exp2 domain + causal mask (only diagonal-crossing tile)
    float xs[4][4];
    const bool needmask = (k0 + 63 > q0);
#pragma unroll
    for (int nt = 0; nt < 4; ++nt)
#pragma unroll
      for (int r = 0; r < 4; ++r) {
        float xv = s[nt][r] * cscale;
        if (needmask && (k0 + nt * 16 + m) > (q0 + quad * 4 + r))
          xv = -__builtin_inff();
        xs[nt][r] = xv;
      }

    float mnew[4], alpha[4];
#pragma unroll
    for (int r = 0; r < 4; ++r) {
      float v = fmaxf(fmaxf(xs[0][r], xs[1][r]), fmaxf(xs[2][r], xs[3][r]));
      v = fmaxf(v, __shfl_xor(v, 1));
      v = fmaxf(v, __shfl_xor(v, 2));
      v = fmaxf(v, __shfl_xor(v, 4));
      v = fmaxf(v, __shfl_xor(v, 8));
      mnew[r] = fmaxf(mrow[r], v);
      alpha[r] = exp2f(mrow[r] - mnew[r]);
      mrow[r] = mnew[r];
    }

    float psum[4] = {0.f, 0.f, 0.f, 0.f};
#pragma unroll
    for (int nt = 0; nt < 4; ++nt)
#pragma unroll
      for (int r = 0; r < 4; ++r) {
        float p = exp2f(xs[nt][r] - mnew[r]);
        psum[r] += p;
        Plw[(quad * 4 + r) * LSTR + nt * 16 + m] = __float2bfloat16(p);
      }
#pragma unroll
    for (int r = 0; r < 4; ++r) {
      float v = psum[r];
      v += __shfl_xor(v, 1);
      v += __shfl_xor(v, 2);
      v += __shfl_xor(v, 4);
      v += __shfl_xor(v, 8);
      lrow[r] = lrow[r] * alpha[r] + v;
    }
#pragma unroll
    for (int nt = 0; nt < 4; ++nt)
#pragma unroll
      for (int r = 0; r < 4; ++r) Oacc[nt][r] *= alpha[r];

    // O += P V
    bf16x8 pf0 = *(const bf16x8*)(&Plw[m * LSTR + quad * 8]);
    bf16x8 pf1 = *(const bf16x8*)(&Plw[m * LSTR + 32 + quad * 8]);
#pragma unroll
    for (int nt = 0; nt < 4; ++nt) {
      Oacc[nt] = __builtin_amdgcn_mfma_f32_16x16x32_bf16(pf0, vf[2 * nt], Oacc[nt], 0, 0, 0);
      Oacc[nt] = __builtin_amdgcn_mfma_f32_16x16x32_bf16(pf1, vf[2 * nt + 1], Oacc[nt], 0, 0, 0);
    }
  }

  float* Op = Opart + (size_t)jid * 1024;
#pragma unroll
  for (int nt = 0; nt < 4; ++nt)
#pragma unroll
    for (int r = 0; r < 4; ++r)
      Op[(quad * 4 + r) * 64 + nt * 16 + m] = Oacc[nt][r];
  if (m == 0) {
#pragma unroll
    for (int r = 0; r < 4; ++r) {
      Ml[(size_t)jid * 32 + quad * 4 + r] = mrow[r];
      Ml[(size_t)jid * 32 + 16 + quad * 4 + r] = lrow[r];
    }
  }
}

// ---- kernel 3: combine partials. 1024 WGs = (b, qtile16); thread = (row, 4 h's).
__global__ __launch_bounds__(256) void fa_combine(
    const float* __restrict__ Opart, const float* __restrict__ Ml,
    float* __restrict__ out) {
  const int bq = blockIdx.x;
  const int b = bq >> 8;
  const int qt = bq & 255;
  const int g = qt >> 5;
  const int nc = g + 1;
  const int jbase = b * 1152 + 16 * g * (g + 1) + (qt & 31) * nc;
  const int r = threadIdx.x >> 4;
  const int h0 = (threadIdx.x & 15) * 4;

  float M = -__builtin_inff();
  for (int c = 0; c < nc; ++c) {
    float mv = Ml[(size_t)(jbase + c) * 32 + r];
    M = fmaxf(M, mv);
  }
  float4 O = {0.f, 0.f, 0.f, 0.f};
  float L = 0.f;
  for (int c = 0; c < nc; ++c) {
    float mv = Ml[(size_t)(jbase + c) * 32 + r];
    float lv = Ml[(size_t)(jbase + c) * 32 + 16 + r];
    float w = exp2f(mv - M);
    float4 o = *(const float4*)(Opart + (size_t)(jbase + c) * 1024 + r * 64 + h0);
    O.x += w * o.x; O.y += w * o.y; O.z += w * o.z; O.w += w * o.w;
    L += w * lv;
  }
  float inv = 1.f / L;
  float4 res = {O.x * inv, O.y * inv, O.z * inv, O.w * inv};
  *(float4*)(out + ((size_t)b * T_ + qt * 16 + r) * H_ + h0) = res;
}

extern "C" void kernel_launch(void* const* d_in, const int* in_sizes, int n_in,
                              void* d_out, int out_size, void* d_ws, size_t ws_size,
                              hipStream_t stream) {
  const float* x = (const float*)d_in[0];
  const float* Wk = (const float*)d_in[1];
  const float* Wq = (const float*)d_in[2];
  const float* Wv = (const float*)d_in[3];
  float* out = (float*)d_out;
  char* ws = (char*)d_ws;
  // ws: Wt[192][1024]bf16 | qb[4][4096][64]bf16 | Kf[4][64][4096]bf16(frag order)
  //     | Vf same | Opart[4608][16][64]f32 | Ml[4608][2][16]f32   (~26.1 MB)
  __hip_bfloat16* Wt = (__hip_bfloat16*)ws;
  __hip_bfloat16* qb = (__hip_bfloat16*)(ws + 393216);
  __hip_bfloat16* Kf = (__hip_bfloat16*)(ws + 2490368);
  __hip_bfloat16* Vf = (__hip_bfloat16*)(ws + 4587520);
  float* Opart = (float*)(ws + 6684672);
  float* Ml = (float*)(ws + 25559040);

  hipLaunchKernelGGL(wtrans_kernel, dim3(768), dim3(256), 0, stream, Wk, Wq, Wv, Wt);
  hipLaunchKernelGGL(proj_kernel, dim3(1024), dim3(256), 0, stream, x, Wt, qb, Kf, Vf);
  hipLaunchKernelGGL(fa_pass1, dim3(1152), dim3(256), 0, stream, qb, Kf, Vf, Opart, Ml);
  hipLaunchKernelGGL(fa_combine, dim3(1024), dim3(256), 0, stream, Opart, Ml, out);
}